// Round 1
// 558.565 us; speedup vs baseline: 1.0645x; 1.0645x over previous
//
#include <hip/hip_runtime.h>

// Luong dot attention, B=8, T=S=2048, D=1024, fp32 in/out.
// Fast path (ws >= 192 MiB):
//   P1: trg -> fp16
//   P2: src -> fp16 hi + fp16 lo + fp16 transposed (hi)
//   G1: scores = trg16 @ (srcHi+srcLo)^T  fp16 2-pass, 256x256 tile, BK=32,
//       triple-buffered LDS + counted vmcnt pipeline (no vmcnt(0) in loop)
//   SM: softmax fp32 in place + fp16 weights (single-wave blocks)
//   G2: context = w16 @ srcT16, same pipelined 256x256 structure
// Fallback = round-1 kernels.

#define BB 8
#define TT 2048
#define SS 2048
#define DD 1024

typedef float  f32x4   __attribute__((ext_vector_type(4)));
typedef float  f32x16  __attribute__((ext_vector_type(16)));
typedef short  bf16x8  __attribute__((ext_vector_type(8)));
typedef _Float16 f16x8 __attribute__((ext_vector_type(8)));
typedef _Float16 f16x4 __attribute__((ext_vector_type(4)));

static __device__ __forceinline__ unsigned short bf16_rne(float x) {
  unsigned int u = __float_as_uint(x);
  u += 0x7FFFu + ((u >> 16) & 1u);
  return (unsigned short)(u >> 16);
}

static __device__ __forceinline__ void gl2lds16(const void* g, void* l) {
  __builtin_amdgcn_global_load_lds(
      (const __attribute__((address_space(1))) unsigned int*)g,
      (__attribute__((address_space(3))) unsigned int*)l, 16, 0, 0);
}

// ---------------------------------------------------------------------------
// P1: trg fp32 -> fp16 (single).
// ---------------------------------------------------------------------------
__global__ __launch_bounds__(256)
void conv_trg_f16(const float* __restrict__ x, _Float16* __restrict__ h16) {
  const size_t i = ((size_t)blockIdx.x * 256 + threadIdx.x) * 8;
  float4 v0 = *(const float4*)(x + i);
  float4 v1 = *(const float4*)(x + i + 4);
  f16x8 h;
  h[0] = (_Float16)v0.x; h[1] = (_Float16)v0.y;
  h[2] = (_Float16)v0.z; h[3] = (_Float16)v0.w;
  h[4] = (_Float16)v1.x; h[5] = (_Float16)v1.y;
  h[6] = (_Float16)v1.z; h[7] = (_Float16)v1.w;
  *(f16x8*)(h16 + i) = h;
}

// ---------------------------------------------------------------------------
// P2: src fp32 -> fp16 hi + fp16 lo ([S][D]) + fp16 transposed hi ([D][S]).
// ---------------------------------------------------------------------------
__global__ __launch_bounds__(256)
void conv_src_f16_hilo_t(const float* __restrict__ src,
                         _Float16* __restrict__ hi,
                         _Float16* __restrict__ lo,
                         _Float16* __restrict__ srcT) {
  const int b  = blockIdx.z;
  const int d0 = blockIdx.x * 64;
  const int s0 = blockIdx.y * 64;
  const float* S = src + (size_t)b * SS * DD;
  __shared__ _Float16 t16[64][65];
  const int t = threadIdx.x;

#pragma unroll
  for (int p = 0; p < 4; ++p) {
    const int r = p * 16 + (t >> 4);
    const int c = (t & 15) * 4;
    float4 v = *(const float4*)(S + (size_t)(s0 + r) * DD + d0 + c);
    float f[4] = {v.x, v.y, v.z, v.w};
    f16x4 h, l;
#pragma unroll
    for (int e = 0; e < 4; ++e) {
      _Float16 hv = (_Float16)f[e];
      h[e] = hv;
      l[e] = (_Float16)(f[e] - (float)hv);
      t16[r][c + e] = hv;
    }
    const size_t go = ((size_t)b * SS + s0 + r) * DD + d0 + c;
    *(f16x4*)(hi + go) = h;
    *(f16x4*)(lo + go) = l;
  }
  __syncthreads();
#pragma unroll
  for (int p = 0; p < 4; ++p) {
    const int d  = p * 16 + (t >> 4);
    const int sq = (t & 15) * 4;
    f16x4 o;
#pragma unroll
    for (int k = 0; k < 4; ++k) o[k] = t16[sq + k][d];
    *(f16x4*)(srcT + ((size_t)b * DD + d0 + d) * SS + s0 + sq) = o;
  }
}

// ---------------------------------------------------------------------------
// G1: scores = trg16 @ src16^T, fp16 2-pass (A single, B hi+lo).
// 256x256 tile, BK=32, 8 waves (2Mx4N, per-wave 128x64), 32x32x16 MFMA.
// Triple-buffered LDS, counted vmcnt, raw s_barrier (no vmcnt(0) drain).
// LDS layout per buffer: A[256x32] | Bh[256x32] | Bl[256x32], each row =
// 4 groups of 8 halves, group slot XOR-swizzled by ((row>>1)&3).
// ---------------------------------------------------------------------------
__global__ __launch_bounds__(512, 2)
void attn_gemm1_pipe(const _Float16* __restrict__ a16,
                     const _Float16* __restrict__ bh16,
                     const _Float16* __restrict__ bl16,
                     float* __restrict__ scores) {
  const int b   = blockIdx.z;
  const int tm0 = blockIdx.y * 256;
  const int tn0 = blockIdx.x * 256;
  float* C = scores + (size_t)b * TT * SS;

  // 3 buffers x 3 matrices x 8192 halves (16 KB) = 144 KB
  __shared__ __align__(16) _Float16 sm[3][3][8192];

  const int t      = threadIdx.x;            // 0..511
  const int lane   = t & 63;
  const int wv     = t >> 6;                 // 0..7
  const int wm     = (wv >> 2) * 128;        // 0 / 128
  const int wn     = (wv & 3) * 64;          // 0..192
  const int lrow32 = lane & 31;
  const int khalf  = lane >> 5;

  // staging: 1024 16B-chunks per matrix; thread covers chunks t and t+512
  const int s0 = t, s1 = t + 512;
  const int r0 = s0 >> 2, g0 = (s0 & 3) ^ ((r0 >> 1) & 3);
  const int r1 = s1 >> 2, g1 = (s1 & 3) ^ ((r1 >> 1) & 3);

  const _Float16* pA0  = a16  + ((size_t)b * TT + tm0 + r0) * DD + g0 * 8;
  const _Float16* pA1  = a16  + ((size_t)b * TT + tm0 + r1) * DD + g1 * 8;
  const _Float16* pBh0 = bh16 + ((size_t)b * SS + tn0 + r0) * DD + g0 * 8;
  const _Float16* pBh1 = bh16 + ((size_t)b * SS + tn0 + r1) * DD + g1 * 8;
  const _Float16* pBl0 = bl16 + ((size_t)b * SS + tn0 + r0) * DD + g0 * 8;
  const _Float16* pBl1 = bl16 + ((size_t)b * SS + tn0 + r1) * DD + g1 * 8;

#define STAGE1(dst)                                    \
  do {                                                 \
    gl2lds16(pA0,  (dst) + s0 * 8);                    \
    gl2lds16(pA1,  (dst) + s1 * 8);                    \
    gl2lds16(pBh0, (dst) + 8192 + s0 * 8);             \
    gl2lds16(pBh1, (dst) + 8192 + s1 * 8);             \
    gl2lds16(pBl0, (dst) + 16384 + s0 * 8);            \
    gl2lds16(pBl1, (dst) + 16384 + s1 * 8);            \
    pA0 += 32; pA1 += 32; pBh0 += 32; pBh1 += 32;      \
    pBl0 += 32; pBl1 += 32;                            \
  } while (0)

  f32x16 acc[4][2];
#pragma unroll
  for (int i = 0; i < 4; ++i)
#pragma unroll
    for (int j = 0; j < 2; ++j) acc[i][j] = (f32x16)0.0f;

  _Float16* bufc = &sm[0][0][0];   // compute
  _Float16* bufo = &sm[1][0][0];   // next (landed before we read it)
  _Float16* bufn = &sm[2][0][0];   // stage target (tile t+2)

  // prologue: tiles 0 and 1 in flight; wait for tile 0 only (6 newest stay).
  STAGE1(bufc);
  STAGE1(bufo);
  asm volatile("s_waitcnt vmcnt(6)" ::: "memory");
  __builtin_amdgcn_s_barrier();
  __builtin_amdgcn_sched_barrier(0);

  const int NT = DD / 32;  // 32 K-tiles
#pragma unroll 1
  for (int tt = 0; tt < NT; ++tt) {
    if (tt + 2 < NT) STAGE1(bufn);  // into buffer holding dead tile tt-1

    const _Float16* As = bufc;
    const _Float16* Bh = bufc + 8192;
    const _Float16* Bl = bufc + 16384;
#pragma unroll
    for (int kk = 0; kk < 2; ++kk) {
      const int cb = kk * 2 + khalf;
      f16x8 a[4], bh[2], bl[2];
#pragma unroll
      for (int mi = 0; mi < 4; ++mi) {
        const int r = wm + mi * 32 + lrow32;
        a[mi] = *(const f16x8*)(As + (r * 4 + (cb ^ ((r >> 1) & 3))) * 8);
      }
#pragma unroll
      for (int ni = 0; ni < 2; ++ni) {
        const int r   = wn + ni * 32 + lrow32;
        const int off = (r * 4 + (cb ^ ((r >> 1) & 3))) * 8;
        bh[ni] = *(const f16x8*)(Bh + off);
        bl[ni] = *(const f16x8*)(Bl + off);
      }
      __builtin_amdgcn_s_setprio(1);
#pragma unroll
      for (int mi = 0; mi < 4; ++mi)
#pragma unroll
        for (int ni = 0; ni < 2; ++ni) {
          acc[mi][ni] = __builtin_amdgcn_mfma_f32_32x32x16_f16(a[mi], bh[ni], acc[mi][ni], 0, 0, 0);
          acc[mi][ni] = __builtin_amdgcn_mfma_f32_32x32x16_f16(a[mi], bl[ni], acc[mi][ni], 0, 0, 0);
        }
      __builtin_amdgcn_s_setprio(0);
    }

    // tile tt+1 must be fully landed for ALL waves before next iteration:
    // per-wave counted wait + barrier gives the cross-wave guarantee while
    // tile tt+2's 6 loads stay in flight.
    if (tt + 2 < NT) asm volatile("s_waitcnt vmcnt(6)" ::: "memory");
    else             asm volatile("s_waitcnt vmcnt(0)" ::: "memory");
    __builtin_amdgcn_s_barrier();
    __builtin_amdgcn_sched_barrier(0);

    _Float16* tmp = bufc; bufc = bufo; bufo = bufn; bufn = tmp;
  }
#undef STAGE1

  // C/D 32x32: col=lane&31, row=(p&3)+8*(p>>2)+4*(lane>>5)
  const int rsub = 4 * khalf;
#pragma unroll
  for (int mi = 0; mi < 4; ++mi)
#pragma unroll
    for (int ni = 0; ni < 2; ++ni) {
      const int rb  = tm0 + wm + mi * 32 + rsub;
      const int col = tn0 + wn + ni * 32 + lrow32;
#pragma unroll
      for (int p = 0; p < 16; ++p)
        C[(size_t)(rb + (p & 3) + 8 * (p >> 2)) * SS + col] = acc[mi][ni][p];
    }
}

// ---------------------------------------------------------------------------
// SM: single-wave blocks. 32 floats/lane, shuffle-only.
// ---------------------------------------------------------------------------
__global__ __launch_bounds__(64)
void attn_softmax_w16(float* __restrict__ w, _Float16* __restrict__ w16) {
  const size_t row = blockIdx.x;
  float4* p4 = (float4*)(w + row * SS);
  _Float16* o = w16 + row * SS;
  const int lane = threadIdx.x;

  float4 v[8];
#pragma unroll
  for (int j = 0; j < 8; ++j) v[j] = p4[lane + 64 * j];

  float m = -1e30f;
#pragma unroll
  for (int j = 0; j < 8; ++j)
    m = fmaxf(m, fmaxf(fmaxf(v[j].x, v[j].y), fmaxf(v[j].z, v[j].w)));
#pragma unroll
  for (int off = 32; off >= 1; off >>= 1) m = fmaxf(m, __shfl_xor(m, off, 64));

  float s = 0.0f;
#pragma unroll
  for (int j = 0; j < 8; ++j) {
    v[j].x = __expf(v[j].x - m); v[j].y = __expf(v[j].y - m);
    v[j].z = __expf(v[j].z - m); v[j].w = __expf(v[j].w - m);
    s += v[j].x + v[j].y + v[j].z + v[j].w;
  }
#pragma unroll
  for (int off = 32; off >= 1; off >>= 1) s += __shfl_xor(s, off, 64);

  const float inv = __fdividef(1.0f, s);
#pragma unroll
  for (int j = 0; j < 8; ++j) {
    v[j].x *= inv; v[j].y *= inv; v[j].z *= inv; v[j].w *= inv;
    p4[lane + 64 * j] = v[j];
    f16x4 h;
    h[0] = (_Float16)v[j].x; h[1] = (_Float16)v[j].y;
    h[2] = (_Float16)v[j].z; h[3] = (_Float16)v[j].w;
    *(f16x4*)(o + 4 * (lane + 64 * j)) = h;
  }
}

// ---------------------------------------------------------------------------
// G2: context = w16 @ srcT16. Same pipelined 256x256 / BK=32 structure,
// 2 staged matrices, steady-state vmcnt(4).
// ---------------------------------------------------------------------------
__global__ __launch_bounds__(512, 2)
void attn_gemm2_pipe(const _Float16* __restrict__ w16,
                     const _Float16* __restrict__ srcT,
                     float* __restrict__ out) {
  const int b   = blockIdx.z;
  const int tm0 = blockIdx.y * 256;
  const int tn0 = blockIdx.x * 256;
  float* C = out + (size_t)b * TT * DD;

  // 3 buffers x 2 matrices x 8192 halves = 96 KB
  __shared__ __align__(16) _Float16 sm[3][2][8192];

  const int t      = threadIdx.x;
  const int lane   = t & 63;
  const int wv     = t >> 6;
  const int wm     = (wv >> 2) * 128;
  const int wn     = (wv & 3) * 64;
  const int lrow32 = lane & 31;
  const int khalf  = lane >> 5;

  const int s0 = t, s1 = t + 512;
  const int r0 = s0 >> 2, g0 = (s0 & 3) ^ ((r0 >> 1) & 3);
  const int r1 = s1 >> 2, g1 = (s1 & 3) ^ ((r1 >> 1) & 3);

  const _Float16* pA0 = w16  + ((size_t)b * TT + tm0 + r0) * SS + g0 * 8;
  const _Float16* pA1 = w16  + ((size_t)b * TT + tm0 + r1) * SS + g1 * 8;
  const _Float16* pB0 = srcT + ((size_t)b * DD + tn0 + r0) * SS + g0 * 8;
  const _Float16* pB1 = srcT + ((size_t)b * DD + tn0 + r1) * SS + g1 * 8;

#define STAGE2(dst)                                    \
  do {                                                 \
    gl2lds16(pA0, (dst) + s0 * 8);                     \
    gl2lds16(pA1, (dst) + s1 * 8);                     \
    gl2lds16(pB0, (dst) + 8192 + s0 * 8);              \
    gl2lds16(pB1, (dst) + 8192 + s1 * 8);              \
    pA0 += 32; pA1 += 32; pB0 += 32; pB1 += 32;        \
  } while (0)

  f32x16 acc[4][2];
#pragma unroll
  for (int i = 0; i < 4; ++i)
#pragma unroll
    for (int j = 0; j < 2; ++j) acc[i][j] = (f32x16)0.0f;

  _Float16* bufc = &sm[0][0][0];
  _Float16* bufo = &sm[1][0][0];
  _Float16* bufn = &sm[2][0][0];

  STAGE2(bufc);
  STAGE2(bufo);
  asm volatile("s_waitcnt vmcnt(4)" ::: "memory");
  __builtin_amdgcn_s_barrier();
  __builtin_amdgcn_sched_barrier(0);

  const int NT = SS / 32;  // 64 K-tiles
#pragma unroll 1
  for (int tt = 0; tt < NT; ++tt) {
    if (tt + 2 < NT) STAGE2(bufn);

    const _Float16* As = bufc;
    const _Float16* Bs = bufc + 8192;
#pragma unroll
    for (int kk = 0; kk < 2; ++kk) {
      const int cb = kk * 2 + khalf;
      f16x8 a[4], bf[2];
#pragma unroll
      for (int mi = 0; mi < 4; ++mi) {
        const int r = wm + mi * 32 + lrow32;
        a[mi] = *(const f16x8*)(As + (r * 4 + (cb ^ ((r >> 1) & 3))) * 8);
      }
#pragma unroll
      for (int ni = 0; ni < 2; ++ni) {
        const int r = wn + ni * 32 + lrow32;
        bf[ni] = *(const f16x8*)(Bs + (r * 4 + (cb ^ ((r >> 1) & 3))) * 8);
      }
      __builtin_amdgcn_s_setprio(1);
#pragma unroll
      for (int mi = 0; mi < 4; ++mi)
#pragma unroll
        for (int ni = 0; ni < 2; ++ni)
          acc[mi][ni] = __builtin_amdgcn_mfma_f32_32x32x16_f16(a[mi], bf[ni], acc[mi][ni], 0, 0, 0);
      __builtin_amdgcn_s_setprio(0);
    }

    if (tt + 2 < NT) asm volatile("s_waitcnt vmcnt(4)" ::: "memory");
    else             asm volatile("s_waitcnt vmcnt(0)" ::: "memory");
    __builtin_amdgcn_s_barrier();
    __builtin_amdgcn_sched_barrier(0);

    _Float16* tmp = bufc; bufc = bufo; bufo = bufn; bufn = tmp;
  }
#undef STAGE2

  const int rsub = 4 * khalf;
#pragma unroll
  for (int mi = 0; mi < 4; ++mi)
#pragma unroll
    for (int ni = 0; ni < 2; ++ni) {
      const int rb  = tm0 + wm + mi * 32 + rsub;
      const int col = tn0 + wn + ni * 32 + lrow32;
#pragma unroll
      for (int p = 0; p < 16; ++p)
        C[(size_t)(rb + (p & 3) + 8 * (p >> 2)) * DD + col] = acc[mi][ni][p];
    }
}

// ===========================================================================
// Fallback path (round-1 kernels, no workspace).
// ===========================================================================
__global__ __launch_bounds__(256, 1)
void attn_gemm1_scores_bf16x3(const float* __restrict__ trg,
                              const float* __restrict__ src,
                              float* __restrict__ scores) {
  const int b   = blockIdx.z;
  const int tm0 = blockIdx.y * 128;
  const int tn0 = blockIdx.x * 128;
  const float* A  = trg + (size_t)b * TT * DD;
  const float* Bm = src + (size_t)b * SS * DD;
  float* C = scores + (size_t)b * TT * SS;

  __shared__ __align__(16) unsigned short smAh[128 * 32];
  __shared__ __align__(16) unsigned short smAl[128 * 32];
  __shared__ __align__(16) unsigned short smBh[128 * 32];
  __shared__ __align__(16) unsigned short smBl[128 * 32];

  const int t     = threadIdx.x;
  const int lane  = t & 63;
  const int wv    = t >> 6;
  const int m_off = (wv & 1) * 64;
  const int n_off = (wv >> 1) * 64;
  const int q     = lane >> 4;
  const int lrow  = lane & 15;

  f32x4 acc[4][4];
#pragma unroll
  for (int i = 0; i < 4; ++i)
#pragma unroll
    for (int j = 0; j < 4; ++j) acc[i][j] = (f32x4)0.0f;

  for (int kt = 0; kt < DD; kt += 32) {
    __syncthreads();
#pragma unroll
    for (int h = 0; h < 2; ++h) {
      const int c  = t + h * 256;
      const int r  = c >> 2;
      const int j  = c & 3;
      const int gk = j ^ ((r >> 1) & 3);
      {
        const float* ga = A + (size_t)(tm0 + r) * DD + kt + gk * 8;
        float4 v0 = *(const float4*)ga;
        float4 v1 = *(const float4*)(ga + 4);
        float f[8] = {v0.x, v0.y, v0.z, v0.w, v1.x, v1.y, v1.z, v1.w};
        bf16x8 hi, lo;
#pragma unroll
        for (int e = 0; e < 8; ++e) {
          unsigned short hb = bf16_rne(f[e]);
          hi[e] = (short)hb;
          float hf = __uint_as_float(((unsigned int)hb) << 16);
          lo[e] = (short)bf16_rne(f[e] - hf);
        }
        *(bf16x8*)(smAh + c * 8) = hi;
        *(bf16x8*)(smAl + c * 8) = lo;
      }
      {
        const float* gb = Bm + (size_t)(tn0 + r) * DD + kt + gk * 8;
        float4 v0 = *(const float4*)gb;
        float4 v1 = *(const float4*)(gb + 4);
        float f[8] = {v0.x, v0.y, v0.z, v0.w, v1.x, v1.y, v1.z, v1.w};
        bf16x8 hi, lo;
#pragma unroll
        for (int e = 0; e < 8; ++e) {
          unsigned short hb = bf16_rne(f[e]);
          hi[e] = (short)hb;
          float hf = __uint_as_float(((unsigned int)hb) << 16);
          lo[e] = (short)bf16_rne(f[e] - hf);
        }
        *(bf16x8*)(smBh + c * 8) = hi;
        *(bf16x8*)(smBl + c * 8) = lo;
      }
    }
    __syncthreads();

    bf16x8 ah[4], al[4], bh[4], bl[4];
#pragma unroll
    for (int mi = 0; mi < 4; ++mi) {
      const int r   = m_off + mi * 16 + lrow;
      const int off = (r * 4 + (q ^ ((r >> 1) & 3))) * 8;
      ah[mi] = *(const bf16x8*)(smAh + off);
      al[mi] = *(const bf16x8*)(smAl + off);
    }
#pragma unroll
    for (int ni = 0; ni < 4; ++ni) {
      const int r   = n_off + ni * 16 + lrow;
      const int off = (r * 4 + (q ^ ((r >> 1) & 3))) * 8;
      bh[ni] = *(const bf16x8*)(smBh + off);
      bl[ni] = *(const bf16x8*)(smBl + off);
    }
#pragma unroll
    for (int mi = 0; mi < 4; ++mi)
#pragma unroll
      for (int ni = 0; ni < 4; ++ni) {
        acc[mi][ni] = __builtin_amdgcn_mfma_f32_16x16x32_bf16(al[mi], bh[ni], acc[mi][ni], 0, 0, 0);
        acc[mi][ni] = __builtin_amdgcn_mfma_f32_16x16x32_bf16(ah[mi], bl[ni], acc[mi][ni], 0, 0, 0);
        acc[mi][ni] = __builtin_amdgcn_mfma_f32_16x16x32_bf16(ah[mi], bh[ni], acc[mi][ni], 0, 0, 0);
      }
  }

#pragma unroll
  for (int mi = 0; mi < 4; ++mi)
#pragma unroll
    for (int ni = 0; ni < 4; ++ni) {
      const int row0 = tm0 + m_off + mi * 16 + q * 4;
      const int col  = tn0 + n_off + ni * 16 + lrow;
#pragma unroll
      for (int p = 0; p < 4; ++p)
        C[(size_t)(row0 + p) * SS + col] = acc[mi][ni][p];
    }
}

__global__ __launch_bounds__(256)
void attn_softmax_rows(float* __restrict__ w) {
  float* p = w + (size_t)blockIdx.x * SS;
  const int t = threadIdx.x;
  float4* p4 = (float4*)p;
  float4 v0 = p4[t];
  float4 v1 = p4[t + 256];

  float m = fmaxf(fmaxf(fmaxf(v0.x, v0.y), fmaxf(v0.z, v0.w)),
                  fmaxf(fmaxf(v1.x, v1.y), fmaxf(v1.z, v1.w)));
#pragma unroll
  for (int off = 32; off >= 1; off >>= 1) m = fmaxf(m, __shfl_xor(m, off, 64));
  __shared__ float redm[4];
  __shared__ float reds[4];
  const int wv = t >> 6, lane = t & 63;
  if (lane == 0) redm[wv] = m;
  __syncthreads();
  m = fmaxf(fmaxf(redm[0], redm[1]), fmaxf(redm[2], redm[3]));

  v0.x = __expf(v0.x - m); v0.y = __expf(v0.y - m);
  v0.z = __expf(v0.z - m); v0.w = __expf(v0.w - m);
  v1.x = __expf(v1.x - m); v1.y = __expf(v1.y - m);
  v1.z = __expf(v1.z - m); v1.w = __expf(v1.w - m);

  float s = v0.x + v0.y + v0.z + v0.w + v1.x + v1.y + v1.z + v1.w;
#pragma unroll
  for (int off = 32; off >= 1; off >>= 1) s += __shfl_xor(s, off, 64);
  if (lane == 0) reds[wv] = s;
  __syncthreads();
  s = reds[0] + reds[1] + reds[2] + reds[3];

  const float inv = __fdividef(1.0f, s);
  v0.x *= inv; v0.y *= inv; v0.z *= inv; v0.w *= inv;
  v1.x *= inv; v1.y *= inv; v1.z *= inv; v1.w *= inv;
  p4[t] = v0;
  p4[t + 256] = v1;
}

__global__ __launch_bounds__(256, 1)
void attn_gemm2_ctx_f16(const float* __restrict__ w,
                        const float* __restrict__ src,
                        float* __restrict__ out) {
  const int b   = blockIdx.z;
  const int tm0 = blockIdx.y * 128;
  const int tn0 = blockIdx.x * 128;
  const float* A  = w + (size_t)b * TT * SS;
  const float* Bs = src + (size_t)b * SS * DD;
  float* C = out + (size_t)b * TT * DD;

  __shared__ __align__(16) _Float16 smA[128 * 32];
  __shared__ __align__(16) _Float16 smB[128 * 32];

  const int t     = threadIdx.x;
  const int lane  = t & 63;
  const int wv    = t >> 6;
  const int m_off = (wv & 1) * 64;
  const int n_off = (wv >> 1) * 64;
  const int q     = lane >> 4;
  const int lrow  = lane & 15;

  const int bn    = t & 127;
  const int bh2   = t >> 7;
  const int bs2   = (bn >> 1) & 3;
  const int slot0 = (2 * bh2) ^ bs2;
  const int slot1 = (2 * bh2 + 1) ^ bs2;

  f32x4 acc[4][4];
#pragma unroll
  for (int i = 0; i < 4; ++i)
#pragma unroll
    for (int j = 0; j < 4; ++j) acc[i][j] = (f32x4)0.0f;

  for (int kt = 0; kt < SS; kt += 32) {
    __syncthreads();
#pragma unroll
    for (int h = 0; h < 2; ++h) {
      const int c  = t + h * 256;
      const int r  = c >> 2;
      const int j  = c & 3;
      const int gk = j ^ ((r >> 1) & 3);
      const float* ga = A + (size_t)(tm0 + r) * SS + kt + gk * 8;
      float4 v0 = *(const float4*)ga;
      float4 v1 = *(const float4*)(ga + 4);
      f16x8 hv;
      hv[0] = (_Float16)v0.x; hv[1] = (_Float16)v0.y;
      hv[2] = (_Float16)v0.z; hv[3] = (_Float16)v0.w;
      hv[4] = (_Float16)v1.x; hv[5] = (_Float16)v1.y;
      hv[6] = (_Float16)v1.z; hv[7] = (_Float16)v1.w;
      *(f16x8*)(smA + c * 8) = hv;
    }
    {
      const float* gb = Bs + (size_t)(kt + bh2 * 16) * DD + (tn0 + bn);
      f16x8 c0, c1;
#pragma unroll
      for (int kk = 0; kk < 8; ++kk) c0[kk] = (_Float16)gb[(size_t)kk * DD];
#pragma unroll
      for (int kk = 0; kk < 8; ++kk) c1[kk] = (_Float16)gb[(size_t)(kk + 8) * DD];
      *(f16x8*)(smB + bn * 32 + slot0 * 8) = c0;
      *(f16x8*)(smB + bn * 32 + slot1 * 8) = c1;
    }
    __syncthreads();

    f16x8 af[4], bfr[4];
#pragma unroll
    for (int mi = 0; mi < 4; ++mi) {
      const int r   = m_off + mi * 16 + lrow;
      const int off = (r * 4 + (q ^ ((r >> 1) & 3))) * 8;
      af[mi] = *(const f16x8*)(smA + off);
    }
#pragma unroll
    for (int ni = 0; ni < 4; ++ni) {
      const int n   = n_off + ni * 16 + lrow;
      const int off = n * 32 + (q ^ ((n >> 1) & 3)) * 8;
      bfr[ni] = *(const f16x8*)(smB + off);
    }
#pragma unroll
    for (int mi = 0; mi < 4; ++mi)
#pragma unroll
      for (int ni = 0; ni < 4; ++ni)
        acc[mi][ni] = __builtin_amdgcn_mfma_f32_16x16x32_f16(af[mi], bfr[ni], acc[mi][ni], 0, 0, 0);
  }

#pragma unroll
  for (int mi = 0; mi < 4; ++mi)
#pragma unroll
    for (int ni = 0; ni < 4; ++ni) {
      const int row0 = tm0 + m_off + mi * 16 + q * 4;
      const int col  = tn0 + n_off + ni * 16 + lrow;
#pragma unroll
      for (int p = 0; p < 4; ++p)
        C[(size_t)(row0 + p) * DD + col] = acc[mi][ni][p];
    }
}

extern "C" void kernel_launch(void* const* d_in, const int* in_sizes, int n_in,
                              void* d_out, int out_size, void* d_ws, size_t ws_size,
                              hipStream_t stream) {
  const float* trg = (const float*)d_in[0];
  const float* src = (const float*)d_in[1];
  float* ctx = (float*)d_out;
  float* wts = (float*)d_out + (size_t)BB * TT * DD;

  const size_t NT = (size_t)BB * TT * DD;  // 16,777,216
  const size_t NW = (size_t)BB * TT * SS;  // 33,554,432
  const size_t need = (4 * NT + NW) * 2;   // 201,326,592 B = 192 MiB

  if (ws_size >= need) {
    _Float16* tH16 = (_Float16*)d_ws;
    _Float16* sH16 = tH16 + NT;
    _Float16* sL16 = sH16 + NT;
    _Float16* srcT = sL16 + NT;
    _Float16* w16  = srcT + NT;

    conv_trg_f16<<<dim3(NT / (8 * 256)), 256, 0, stream>>>(trg, tH16);
    conv_src_f16_hilo_t<<<dim3(DD / 64, SS / 64, BB), 256, 0, stream>>>(src, sH16, sL16, srcT);
    attn_gemm1_pipe<<<dim3(SS / 256, TT / 256, BB), 512, 0, stream>>>(tH16, sH16, sL16, wts);
    attn_softmax_w16<<<dim3(BB * TT), 64, 0, stream>>>(wts, w16);
    attn_gemm2_pipe<<<dim3(DD / 256, TT / 256, BB), 512, 0, stream>>>(w16, srcT, ctx);
  } else {
    attn_gemm1_scores_bf16x3<<<dim3(SS / 128, TT / 128, BB), 256, 0, stream>>>(trg, src, wts);
    attn_softmax_rows<<<dim3(BB * TT), 256, 0, stream>>>(wts);
    attn_gemm2_ctx_f16<<<dim3(DD / 128, TT / 128, BB), 256, 0, stream>>>(wts, src, ctx);
  }
}